// Round 11
// baseline (147.586 us; speedup 1.0000x reference)
//
#include <hip/hip_runtime.h>
#include <hip/hip_bf16.h>

typedef __bf16 bf16x8 __attribute__((ext_vector_type(8)));
typedef __bf16 bf16x4 __attribute__((ext_vector_type(4)));
typedef float  f32x4  __attribute__((ext_vector_type(4)));

constexpr int NN = 16384;
constexpr int EE = 64;
constexpr int DD = 128;
constexpr int EG  = 8;     // experts per block

// ---------- pre-pass 1: X f32 -> bf16 row-major [N][D] ----------
__global__ __launch_bounds__(256)
void cvt_x(const float* __restrict__ X, __bf16* __restrict__ Xb) {
    int i = blockIdx.x * 256 + threadIdx.x;
    const float4* src = (const float4*)X;
    float4 v0 = src[2*i], v1 = src[2*i+1];
    bf16x8 p;
    p[0]=(__bf16)v0.x; p[1]=(__bf16)v0.y; p[2]=(__bf16)v0.z; p[3]=(__bf16)v0.w;
    p[4]=(__bf16)v1.x; p[5]=(__bf16)v1.y; p[6]=(__bf16)v1.z; p[7]=(__bf16)v1.w;
    ((bf16x8*)Xb)[i] = p;
}

// ---------- pre-pass 2: W[e][d][f] f32 -> per-expert SWIZZLED bf16 [f][d] ----------
// Element (f,d) at byte (f*256 + d*2) ^ ((f&7)<<4) within expert's 32KB.
// global_load_lds copies linearly; ds_read applies the same XOR (rule #21).
// Half-expert tiles (f in [h*64,(h+1)*64)) are self-contained 16 KB chunks.
__global__ __launch_bounds__(256)
void cvt_wt(const float* __restrict__ W, __bf16* __restrict__ WTs) {
    __shared__ __bf16 T[DD][DD + 1];
    const int e = blockIdx.x;
    const int t = threadIdx.x;
    const float4* Wg = (const float4*)(W + (size_t)e * DD * DD);
    #pragma unroll
    for (int i = 0; i < 16; ++i) {
        int ft = i * 256 + t;
        int d = ft >> 5, f0 = (ft & 31) * 4;
        float4 v = Wg[ft];
        T[f0+0][d] = (__bf16)v.x;
        T[f0+1][d] = (__bf16)v.y;
        T[f0+2][d] = (__bf16)v.z;
        T[f0+3][d] = (__bf16)v.w;
    }
    __syncthreads();
    char* out = (char*)WTs + (size_t)e * DD * DD * 2;
    #pragma unroll
    for (int i = 0; i < 8; ++i) {
        int ft = i * 256 + t;
        int f = ft >> 4, d0 = (ft & 15) * 8;
        bf16x8 p;
        #pragma unroll
        for (int j = 0; j < 8; ++j) p[j] = T[f][d0 + j];
        int off = f * 256 + d0 * 2;
        off ^= (f & 7) << 4;
        *(bf16x8*)(out + off) = p;
    }
}

__device__ __forceinline__ void gll16(const void* g, void* l) {
    __builtin_amdgcn_global_load_lds(
        (const __attribute__((address_space(1))) void*)g,
        (__attribute__((address_space(3))) void*)l, 16, 0, 0);
}

// ---------- main GEMM: 512 thr / 8 waves, 128 rows x 8 experts ----------
// CHANGE vs R10 (isolated): W streamed as HALF-EXPERT tiles (16 KB dbuf) and
// obuf shrunk to 32 KB -> 64 KB LDS total -> 2 blocks/CU (was 1). Wave owns
// 16 rows x 64-col half per step; 16 steps. Bias software-pipelined so its
// consumption wait doesn't retire in-flight stores. vmcnt(4) barrier keeps
// each step's 4 stores in flight through the next step's compute.
__global__ __launch_bounds__(512, 4)
void experts_gemm_hs(const __bf16* __restrict__ Xb,
                     const __bf16* __restrict__ WTs,
                     const float* __restrict__ Bias,
                     float* __restrict__ O)
{
    __shared__ __align__(16) char lds[2*16384 + 32768];   // W half dbuf 32K + obuf 32K
    const int t    = threadIdx.x;
    const int lane = t & 63, w = t >> 6;          // w 0..7
    const int l15  = lane & 15, kg = lane >> 4;
    const int eg   = blockIdx.x & (EE/EG - 1);
    const int n0   = (blockIdx.x >> 3) * 128;
    const int e0   = eg * EG;
    char* obuf = lds + 32768 + w * 4096;          // wave-private 4 KB

    // X fragments, loaded once: wave rows n0 + w*16 + l15, k = kk*32+kg*8
    bf16x8 a[4];
    {
        const __bf16* Xp = Xb + (size_t)(n0 + w*16 + l15) * DD + kg*8;
        #pragma unroll
        for (int kk = 0; kk < 4; ++kk)
            a[kk] = *(const bf16x8*)(Xp + kk*32);
    }

    // prologue: stage half-step 0 (expert e0, h=0) -> buf 0; bias for step 0
    {
        const char* src = (const char*)WTs + (size_t)e0 * 32768 + w*2048 + lane*16;
        char* dst = lds + w*2048;
        gll16(src, dst);
        gll16(src + 1024, dst + 1024);
    }
    f32x4 bv[4];
    {
        const float* Bp = Bias + e0*DD + kg*4;    // h=0
        #pragma unroll
        for (int n = 0; n < 4; ++n) bv[n] = *(const f32x4*)(Bp + n*16);
    }
    __syncthreads();

    int cur = 0;
    for (int s = 0; s < 2*EG; ++s) {
        const int e = e0 + (s >> 1), h = s & 1;

        // prefetch next half-step's W into the other buffer
        if (s + 1 < 2*EG) {
            const int en = e0 + ((s+1) >> 1), hn = (s+1) & 1;
            const char* src = (const char*)WTs + (size_t)en * 32768 + hn*16384
                              + w*2048 + lane*16;
            char* dst = lds + (cur ^ 1) * 16384 + w*2048;
            gll16(src, dst);
            gll16(src + 1024, dst + 1024);
        }

        // acc init = bias (pipelined from previous step)
        f32x4 acc[4];
        #pragma unroll
        for (int n = 0; n < 4; ++n) acc[n] = bv[n];

        // compute: 16 MFMA over the 64-col half
        const char* buf = lds + cur * 16384;
        #pragma unroll
        for (int kk = 0; kk < 4; ++kk) {
            bf16x8 b[4];
            #pragma unroll
            for (int n = 0; n < 4; ++n) {
                int f = n*16 + l15;               // f_local in [0,64)
                int off = f*256 + (kk*32 + kg*8)*2;
                off ^= (l15 & 7) << 4;
                b[n] = *(const bf16x8*)(buf + off);
            }
            #pragma unroll
            for (int n = 0; n < 4; ++n)
                acc[n] = __builtin_amdgcn_mfma_f32_16x16x32_bf16(
                    b[n], a[kk], acc[n], 0, 0, 0);
        }

        // stage acc -> wave-private obuf (16 rows x 256 B, swizzled)
        #pragma unroll
        for (int n = 0; n < 4; ++n) {
            int row = l15;
            int off = row*256 + n*64 + kg*16;
            off ^= (row & 7) << 4;
            *(f32x4*)(obuf + off) = acc[n];
        }

        // pipeline: load bias for NEXT step (older in vm queue than stores)
        if (s + 1 < 2*EG) {
            const int en = e0 + ((s+1) >> 1), hn = (s+1) & 1;
            const float* Bp = Bias + en*DD + hn*64 + kg*4;
            #pragma unroll
            for (int n = 0; n < 4; ++n) bv[n] = *(const f32x4*)(Bp + n*16);
        }
        __builtin_amdgcn_sched_barrier(0);   // keep bias loads before stores

        // readback + stores: 4 insts, each 4 rows x (16 lanes x 16 B = 256 B)
        {
            const int ro = lane >> 4, c16 = lane & 15;
            #pragma unroll
            for (int rg = 0; rg < 4; ++rg) {
                int row = rg*4 + ro;
                int off = row*256 + c16*16;
                off ^= (row & 7) << 4;
                f32x4 v = *(const f32x4*)(obuf + off);
                *(f32x4*)(O + (size_t)(n0 + w*16 + row) * (EE*DD)
                            + e*DD + h*64 + c16*4) = v;
            }
        }

        // counted barrier: retire this step's 2 glls (+ anything older, incl.
        // last step's stores which had a full step to drain); keep the 4
        // newest ops (this step's stores) in flight.
        if (s + 1 < 2*EG) {
            __builtin_amdgcn_sched_barrier(0);
            asm volatile("s_waitcnt vmcnt(4)" ::: "memory");
            __builtin_amdgcn_s_barrier();
            __builtin_amdgcn_sched_barrier(0);
        }
        cur ^= 1;
    }
}

// ---------- fallback (round-0 kernel, used if ws too small) ----------
__global__ __launch_bounds__(256, 2)
void experts_gemm_fb(const float* __restrict__ X,
                     const float* __restrict__ W,
                     const float* __restrict__ Bias,
                     float* __restrict__ O)
{
    constexpr int BM = 128;
    __shared__ __align__(16) char lds[BM*DD*2 + DD*DD*2];
    __bf16* As = (__bf16*)lds;
    __bf16* Bs = (__bf16*)(lds + BM*DD*2);

    const int t   = threadIdx.x;
    const int e   = blockIdx.x & (EE - 1);
    const int n0  = (blockIdx.x >> 6) * BM;

    {
        const float4* Xg = (const float4*)(X + (size_t)n0 * DD);
        #pragma unroll
        for (int i = 0; i < 16; ++i) {
            int ft = i * 256 + t;
            float4 v = Xg[ft];
            int n = ft >> 5, d0 = (ft & 31) << 2;
            bf16x4 p;
            p[0]=(__bf16)v.x; p[1]=(__bf16)v.y; p[2]=(__bf16)v.z; p[3]=(__bf16)v.w;
            int off = n * 256 + d0 * 2;
            off ^= (n & 7) << 4;
            *(bf16x4*)((char*)As + off) = p;
        }
    }
    {
        const float4* Wg = (const float4*)(W + (size_t)e * DD * DD);
        #pragma unroll
        for (int i = 0; i < 4; ++i) {
            int bb = i * 256 + t;
            int db = bb >> 5, fb = bb & 31;
            float4 r0 = Wg[(db*4+0)*32 + fb];
            float4 r1 = Wg[(db*4+1)*32 + fb];
            float4 r2 = Wg[(db*4+2)*32 + fb];
            float4 r3 = Wg[(db*4+3)*32 + fb];
            const float* q0=(const float*)&r0; const float* q1=(const float*)&r1;
            const float* q2=(const float*)&r2; const float* q3=(const float*)&r3;
            #pragma unroll
            for (int j = 0; j < 4; ++j) {
                bf16x4 p;
                p[0]=(__bf16)q0[j]; p[1]=(__bf16)q1[j];
                p[2]=(__bf16)q2[j]; p[3]=(__bf16)q3[j];
                int f = fb * 4 + j;
                int off = f * 256 + db * 8;
                off ^= (f & 7) << 4;
                *(bf16x4*)((char*)Bs + off) = p;
            }
        }
    }
    __syncthreads();

    const int lane = t & 63, w = t >> 6;
    const int wr = w >> 1, wc = w & 1;
    const int l15 = lane & 15, kg = lane >> 4;

    f32x4 acc[4][4];
    #pragma unroll
    for (int m = 0; m < 4; ++m)
        #pragma unroll
        for (int n = 0; n < 4; ++n) {
            acc[m][n][0]=0.f; acc[m][n][1]=0.f; acc[m][n][2]=0.f; acc[m][n][3]=0.f;
        }

    float bias[4];
    #pragma unroll
    for (int n = 0; n < 4; ++n) bias[n] = Bias[e*DD + wc*64 + n*16 + l15];

    #pragma unroll
    for (int kk = 0; kk < 4; ++kk) {
        int koff = kk * 32 + kg * 8;
        bf16x8 av[4], bvv[4];
        #pragma unroll
        for (int m = 0; m < 4; ++m) {
            int row = wr*64 + m*16 + l15;
            int off = row * 256 + koff * 2;
            off ^= (row & 7) << 4;
            av[m] = *(const bf16x8*)((const char*)As + off);
        }
        #pragma unroll
        for (int n = 0; n < 4; ++n) {
            int col = wc*64 + n*16 + l15;
            int off = col * 256 + koff * 2;
            off ^= (col & 7) << 4;
            bvv[n] = *(const bf16x8*)((const char*)Bs + off);
        }
        #pragma unroll
        for (int m = 0; m < 4; ++m)
            #pragma unroll
            for (int n = 0; n < 4; ++n)
                acc[m][n] = __builtin_amdgcn_mfma_f32_16x16x32_bf16(
                    av[m], bvv[n], acc[m][n], 0, 0, 0);
    }

    float* Op = O + (size_t)n0 * (EE*DD) + (size_t)e * DD;
    #pragma unroll
    for (int m = 0; m < 4; ++m)
        #pragma unroll
        for (int n = 0; n < 4; ++n) {
            int cg = wc*64 + n*16 + l15;
            #pragma unroll
            for (int r = 0; r < 4; ++r) {
                int rg = wr*64 + m*16 + kg*4 + r;
                Op[(size_t)rg * (EE*DD) + cg] = acc[m][n][r] + bias[n];
            }
        }
}

extern "C" void kernel_launch(void* const* d_in, const int* in_sizes, int n_in,
                              void* d_out, int out_size, void* d_ws, size_t ws_size,
                              hipStream_t stream) {
    const float* X = (const float*)d_in[0];
    const float* W = (const float*)d_in[1];
    const float* B = (const float*)d_in[2];
    float* O = (float*)d_out;

    const size_t xb_bytes = (size_t)NN * DD * sizeof(__bf16);      // 4 MiB
    const size_t wt_bytes = (size_t)EE * DD * DD * sizeof(__bf16); // 2 MiB

    if (ws_size >= xb_bytes + wt_bytes) {
        __bf16* Xb  = (__bf16*)d_ws;
        __bf16* WTs = (__bf16*)((char*)d_ws + xb_bytes);
        cvt_x<<<NN * DD / 8 / 256, 256, 0, stream>>>(X, Xb);
        cvt_wt<<<EE, 256, 0, stream>>>(W, WTs);
        experts_gemm_hs<<<(NN / 128) * (EE / EG), 512, 0, stream>>>(Xb, WTs, B, O);
    } else {
        experts_gemm_fb<<<(NN / 128) * EE, 256, 0, stream>>>(X, W, B, O);
    }
}

// Round 12
// 134.964 us; speedup vs baseline: 1.0935x; 1.0935x over previous
//
#include <hip/hip_runtime.h>
#include <hip/hip_bf16.h>

typedef __bf16 bf16x8 __attribute__((ext_vector_type(8)));
typedef __bf16 bf16x4 __attribute__((ext_vector_type(4)));
typedef float  f32x4  __attribute__((ext_vector_type(4)));

constexpr int NN = 16384;
constexpr int EE = 64;
constexpr int DD = 128;
constexpr int EG  = 8;     // experts per block

// ---------- pre-pass 1: X f32 -> bf16 row-major [N][D] ----------
__global__ __launch_bounds__(256)
void cvt_x(const float* __restrict__ X, __bf16* __restrict__ Xb) {
    int i = blockIdx.x * 256 + threadIdx.x;
    const float4* src = (const float4*)X;
    float4 v0 = src[2*i], v1 = src[2*i+1];
    bf16x8 p;
    p[0]=(__bf16)v0.x; p[1]=(__bf16)v0.y; p[2]=(__bf16)v0.z; p[3]=(__bf16)v0.w;
    p[4]=(__bf16)v1.x; p[5]=(__bf16)v1.y; p[6]=(__bf16)v1.z; p[7]=(__bf16)v1.w;
    ((bf16x8*)Xb)[i] = p;
}

// ---------- pre-pass 2: W[e][d][f] f32 -> per-expert SWIZZLED bf16 [f][d] ----------
// Element (f,d) at byte (f*256 + d*2) ^ ((f&7)<<4) within expert's 32KB.
// global_load_lds copies linearly; ds_read applies the same XOR (rule #21).
__global__ __launch_bounds__(256)
void cvt_wt(const float* __restrict__ W, __bf16* __restrict__ WTs) {
    __shared__ __bf16 T[DD][DD + 1];
    const int e = blockIdx.x;
    const int t = threadIdx.x;
    const float4* Wg = (const float4*)(W + (size_t)e * DD * DD);
    #pragma unroll
    for (int i = 0; i < 16; ++i) {
        int ft = i * 256 + t;
        int d = ft >> 5, f0 = (ft & 31) * 4;
        float4 v = Wg[ft];
        T[f0+0][d] = (__bf16)v.x;
        T[f0+1][d] = (__bf16)v.y;
        T[f0+2][d] = (__bf16)v.z;
        T[f0+3][d] = (__bf16)v.w;
    }
    __syncthreads();
    char* out = (char*)WTs + (size_t)e * DD * DD * 2;
    #pragma unroll
    for (int i = 0; i < 8; ++i) {
        int ft = i * 256 + t;
        int f = ft >> 4, d0 = (ft & 15) * 8;
        bf16x8 p;
        #pragma unroll
        for (int j = 0; j < 8; ++j) p[j] = T[f][d0 + j];
        int off = f * 256 + d0 * 2;
        off ^= (f & 7) << 4;
        *(bf16x8*)(out + off) = p;
    }
}

__device__ __forceinline__ void gll16(const void* g, void* l) {
    __builtin_amdgcn_global_load_lds(
        (const __attribute__((address_space(1))) void*)g,
        (__attribute__((address_space(3))) void*)l, 16, 0, 0);
}

// ---------- main GEMM: column-partition, 512 thr / 8 waves ----------
// Block = 128 rows x 8 experts. Wave w owns cols [w*16, w*16+16) for ALL
// 128 rows (X frags a[8][4] per wave, identical across waves).
// vs R10: (1) W ds_reads 1x-amplified (each wave reads a distinct 4 KB
// strip; was 4x), (2) obuf repack yields FULL 512 B output rows; each store
// inst writes 1024 B contiguous (2 rows), (3) LDS/expert 288->192 KB.
__global__ __launch_bounds__(512, 1)
void experts_gemm_cw(const __bf16* __restrict__ Xb,
                     const __bf16* __restrict__ WTs,
                     const float* __restrict__ Bias,
                     float* __restrict__ O)
{
    __shared__ __align__(16) char lds[2*32768 + 65536];   // W dbuf 64K + obuf 64K
    char* obuf = lds + 65536;
    const int t    = threadIdx.x;
    const int lane = t & 63, w = t >> 6;          // w 0..7 = col strip
    const int l15  = lane & 15, kg = lane >> 4;
    const int eg   = blockIdx.x & (EE/EG - 1);
    const int n0   = (blockIdx.x >> 3) * 128;
    const int e0   = eg * EG;

    // X fragments: ALL 128 rows (8 m-tiles), k = kk*32+kg*8. ~128 VGPR.
    bf16x8 a[8][4];
    {
        const __bf16* Xp = Xb + (size_t)(n0 + l15) * DD + kg*8;
        #pragma unroll
        for (int m = 0; m < 8; ++m)
            #pragma unroll
            for (int kk = 0; kk < 4; ++kk)
                a[m][kk] = *(const bf16x8*)(Xp + m*16*DD + kk*32);
    }

    // prologue: stage W[e0] (full 32 KB; 4 KB per wave via 4 glls)
    {
        const char* src = (const char*)WTs + (size_t)e0 * 32768 + w*4096 + lane*16;
        char* dst = lds + w*4096;
        #pragma unroll
        for (int i = 0; i < 4; ++i) gll16(src + i*1024, dst + i*1024);
    }
    __syncthreads();

    int cur = 0;
    for (int ei = 0; ei < EG; ++ei) {
        const int e = e0 + ei;

        // bias for this wave's 16-col strip (lane cols = w*16 + kg*4 .. +3)
        f32x4 bv = *(const f32x4*)(Bias + e*DD + w*16 + kg*4);

        // prefetch next expert's W
        if (ei + 1 < EG) {
            const char* src = (const char*)WTs + (size_t)(e+1) * 32768 + w*4096 + lane*16;
            char* dst = lds + (cur ^ 1) * 32768 + w*4096;
            #pragma unroll
            for (int i = 0; i < 4; ++i) gll16(src + i*1024, dst + i*1024);
        }

        f32x4 acc[8];
        #pragma unroll
        for (int m = 0; m < 8; ++m) acc[m] = bv;

        // compute: 1 W-strip ds_read per kk (4 KB total), 32 MFMA
        const char* buf = lds + cur * 32768;
        #pragma unroll
        for (int kk = 0; kk < 4; ++kk) {
            int off = (w*16 + l15)*256 + (kk*32 + kg*8)*2;
            off ^= (l15 & 7) << 4;
            bf16x8 b = *(const bf16x8*)(buf + off);
            #pragma unroll
            for (int m = 0; m < 8; ++m)
                acc[m] = __builtin_amdgcn_mfma_f32_16x16x32_bf16(
                    b, a[m][kk], acc[m], 0, 0, 0);
        }

        // obuf stage: row = m*16+l15 (0..127), wave's 64 B strip at w*64+kg*16
        #pragma unroll
        for (int m = 0; m < 8; ++m) {
            int row = m*16 + l15;
            int off = row*512 + w*64 + kg*16;
            off ^= (row & 7) << 4;
            *(f32x4*)(obuf + off) = acc[m];
        }
        __syncthreads();   // all strips visible

        // readback + store: wave owns rows w*16..+15; per inst 2 FULL rows
        // (lanes 0-31 row r, lanes 32-63 row r+1) = 1024 B contiguous.
        {
            const int c32 = lane & 31, rh = lane >> 5;
            #pragma unroll
            for (int i = 0; i < 8; ++i) {
                int row = w*16 + i*2 + rh;
                int off = row*512 + c32*16;
                off ^= (row & 7) << 4;
                f32x4 v = *(const f32x4*)(obuf + off);
                *(f32x4*)(O + (size_t)(n0 + row) * (EE*DD) + e*DD + c32*4) = v;
            }
        }
        __syncthreads();   // obuf free; W dbuf swap safe
        cur ^= 1;
    }
}

// ---------- fallback (round-0 kernel, used if ws too small) ----------
__global__ __launch_bounds__(256, 2)
void experts_gemm_fb(const float* __restrict__ X,
                     const float* __restrict__ W,
                     const float* __restrict__ Bias,
                     float* __restrict__ O)
{
    constexpr int BM = 128;
    __shared__ __align__(16) char lds[BM*DD*2 + DD*DD*2];
    __bf16* As = (__bf16*)lds;
    __bf16* Bs = (__bf16*)(lds + BM*DD*2);

    const int t   = threadIdx.x;
    const int e   = blockIdx.x & (EE - 1);
    const int n0  = (blockIdx.x >> 6) * BM;

    {
        const float4* Xg = (const float4*)(X + (size_t)n0 * DD);
        #pragma unroll
        for (int i = 0; i < 16; ++i) {
            int ft = i * 256 + t;
            float4 v = Xg[ft];
            int n = ft >> 5, d0 = (ft & 31) << 2;
            bf16x4 p;
            p[0]=(__bf16)v.x; p[1]=(__bf16)v.y; p[2]=(__bf16)v.z; p[3]=(__bf16)v.w;
            int off = n * 256 + d0 * 2;
            off ^= (n & 7) << 4;
            *(bf16x4*)((char*)As + off) = p;
        }
    }
    {
        const float4* Wg = (const float4*)(W + (size_t)e * DD * DD);
        #pragma unroll
        for (int i = 0; i < 4; ++i) {
            int bb = i * 256 + t;
            int db = bb >> 5, fb = bb & 31;
            float4 r0 = Wg[(db*4+0)*32 + fb];
            float4 r1 = Wg[(db*4+1)*32 + fb];
            float4 r2 = Wg[(db*4+2)*32 + fb];
            float4 r3 = Wg[(db*4+3)*32 + fb];
            const float* q0=(const float*)&r0; const float* q1=(const float*)&r1;
            const float* q2=(const float*)&r2; const float* q3=(const float*)&r3;
            #pragma unroll
            for (int j = 0; j < 4; ++j) {
                bf16x4 p;
                p[0]=(__bf16)q0[j]; p[1]=(__bf16)q1[j];
                p[2]=(__bf16)q2[j]; p[3]=(__bf16)q3[j];
                int f = fb * 4 + j;
                int off = f * 256 + db * 8;
                off ^= (f & 7) << 4;
                *(bf16x4*)((char*)Bs + off) = p;
            }
        }
    }
    __syncthreads();

    const int lane = t & 63, w = t >> 6;
    const int wr = w >> 1, wc = w & 1;
    const int l15 = lane & 15, kg = lane >> 4;

    f32x4 acc[4][4];
    #pragma unroll
    for (int m = 0; m < 4; ++m)
        #pragma unroll
        for (int n = 0; n < 4; ++n) {
            acc[m][n][0]=0.f; acc[m][n][1]=0.f; acc[m][n][2]=0.f; acc[m][n][3]=0.f;
        }

    float bias[4];
    #pragma unroll
    for (int n = 0; n < 4; ++n) bias[n] = Bias[e*DD + wc*64 + n*16 + l15];

    #pragma unroll
    for (int kk = 0; kk < 4; ++kk) {
        int koff = kk * 32 + kg * 8;
        bf16x8 av[4], bvv[4];
        #pragma unroll
        for (int m = 0; m < 4; ++m) {
            int row = wr*64 + m*16 + l15;
            int off = row * 256 + koff * 2;
            off ^= (row & 7) << 4;
            av[m] = *(const bf16x8*)((const char*)As + off);
        }
        #pragma unroll
        for (int n = 0; n < 4; ++n) {
            int col = wc*64 + n*16 + l15;
            int off = col * 256 + koff * 2;
            off ^= (col & 7) << 4;
            bvv[n] = *(const bf16x8*)((const char*)Bs + off);
        }
        #pragma unroll
        for (int m = 0; m < 4; ++m)
            #pragma unroll
            for (int n = 0; n < 4; ++n)
                acc[m][n] = __builtin_amdgcn_mfma_f32_16x16x32_bf16(
                    av[m], bvv[n], acc[m][n], 0, 0, 0);
    }

    float* Op = O + (size_t)n0 * (EE*DD) + (size_t)e * DD;
    #pragma unroll
    for (int m = 0; m < 4; ++m)
        #pragma unroll
        for (int n = 0; n < 4; ++n) {
            int cg = wc*64 + n*16 + l15;
            #pragma unroll
            for (int r = 0; r < 4; ++r) {
                int rg = wr*64 + m*16 + kg*4 + r;
                Op[(size_t)rg * (EE*DD) + cg] = acc[m][n][r] + bias[n];
            }
        }
}

extern "C" void kernel_launch(void* const* d_in, const int* in_sizes, int n_in,
                              void* d_out, int out_size, void* d_ws, size_t ws_size,
                              hipStream_t stream) {
    const float* X = (const float*)d_in[0];
    const float* W = (const float*)d_in[1];
    const float* B = (const float*)d_in[2];
    float* O = (float*)d_out;

    const size_t xb_bytes = (size_t)NN * DD * sizeof(__bf16);      // 4 MiB
    const size_t wt_bytes = (size_t)EE * DD * DD * sizeof(__bf16); // 2 MiB

    if (ws_size >= xb_bytes + wt_bytes) {
        __bf16* Xb  = (__bf16*)d_ws;
        __bf16* WTs = (__bf16*)((char*)d_ws + xb_bytes);
        cvt_x<<<NN * DD / 8 / 256, 256, 0, stream>>>(X, Xb);
        cvt_wt<<<EE, 256, 0, stream>>>(W, WTs);
        experts_gemm_cw<<<(NN / 128) * (EE / EG), 512, 0, stream>>>(Xb, WTs, B, O);
    } else {
        experts_gemm_fb<<<(NN / 128) * EE, 256, 0, stream>>>(X, W, B, O);
    }
}

// Round 13
// 118.812 us; speedup vs baseline: 1.2422x; 1.1359x over previous
//
#include <hip/hip_runtime.h>
#include <hip/hip_bf16.h>

typedef __bf16 bf16x8 __attribute__((ext_vector_type(8)));
typedef __bf16 bf16x4 __attribute__((ext_vector_type(4)));
typedef float  f32x4  __attribute__((ext_vector_type(4)));

constexpr int NN = 16384;
constexpr int EE = 64;
constexpr int DD = 128;
constexpr int EG  = 8;     // experts per block

// ---------- pre-pass 1: X f32 -> bf16 row-major [N][D] ----------
__global__ __launch_bounds__(256)
void cvt_x(const float* __restrict__ X, __bf16* __restrict__ Xb) {
    int i = blockIdx.x * 256 + threadIdx.x;
    const float4* src = (const float4*)X;
    float4 v0 = src[2*i], v1 = src[2*i+1];
    bf16x8 p;
    p[0]=(__bf16)v0.x; p[1]=(__bf16)v0.y; p[2]=(__bf16)v0.z; p[3]=(__bf16)v0.w;
    p[4]=(__bf16)v1.x; p[5]=(__bf16)v1.y; p[6]=(__bf16)v1.z; p[7]=(__bf16)v1.w;
    ((bf16x8*)Xb)[i] = p;
}

// ---------- pre-pass 2: W[e][d][f] f32 -> per-expert SWIZZLED bf16 [f][d] ----------
// Element (f,d) at byte (f*256 + d*2) ^ ((f&7)<<4) within expert's 32KB.
// global_load_lds copies linearly; ds_read applies the same XOR (rule #21).
__global__ __launch_bounds__(256)
void cvt_wt(const float* __restrict__ W, __bf16* __restrict__ WTs) {
    __shared__ __bf16 T[DD][DD + 1];
    const int e = blockIdx.x;
    const int t = threadIdx.x;
    const float4* Wg = (const float4*)(W + (size_t)e * DD * DD);
    #pragma unroll
    for (int i = 0; i < 16; ++i) {
        int ft = i * 256 + t;
        int d = ft >> 5, f0 = (ft & 31) * 4;
        float4 v = Wg[ft];
        T[f0+0][d] = (__bf16)v.x;
        T[f0+1][d] = (__bf16)v.y;
        T[f0+2][d] = (__bf16)v.z;
        T[f0+3][d] = (__bf16)v.w;
    }
    __syncthreads();
    char* out = (char*)WTs + (size_t)e * DD * DD * 2;
    #pragma unroll
    for (int i = 0; i < 8; ++i) {
        int ft = i * 256 + t;
        int f = ft >> 4, d0 = (ft & 15) * 8;
        bf16x8 p;
        #pragma unroll
        for (int j = 0; j < 8; ++j) p[j] = T[f][d0 + j];
        int off = f * 256 + d0 * 2;
        off ^= (f & 7) << 4;
        *(bf16x8*)(out + off) = p;
    }
}

__device__ __forceinline__ void gll16(const void* g, void* l) {
    __builtin_amdgcn_global_load_lds(
        (const __attribute__((address_space(1))) void*)g,
        (__attribute__((address_space(3))) void*)l, 16, 0, 0);
}

// ---------- main GEMM: 512 thr / 8 waves, 128 rows x 8 experts ----------
// Wave (wr 0..3, wc 0..1) computes 32 rows x 64 cols per expert.
// CHANGE vs R10 (isolated): bias for all 8 experts staged to LDS at the
// prologue; per-expert bias comes via ds_read (lgkm, NOT vmcnt). The
// steady-state loop has ZERO vm loads -> the previous expert's 8 stores
// drain across the whole compute+stage+readback phase instead of being
// force-retired by the bias-load's vmcnt wait at compute start (the R10
// serialization bug). End-of-iter barrier: vmcnt(8) retires glls, keeps
// this expert's 8 stores in flight.
__global__ __launch_bounds__(512, 1)
void experts_gemm_ls(const __bf16* __restrict__ Xb,
                     const __bf16* __restrict__ WTs,
                     const float* __restrict__ Bias,
                     float* __restrict__ O)
{
    __shared__ __align__(16) char lds[2*32768 + 65536 + 4096]; // Wdbuf|obuf|bias
    const int t    = threadIdx.x;
    const int lane = t & 63, w = t >> 6;          // w 0..7
    const int l15  = lane & 15, kg = lane >> 4;
    const int wr   = w >> 1, wc = w & 1;          // 4 row-groups x 2 col-halves
    const int eg   = blockIdx.x & (EE/EG - 1);
    const int n0   = (blockIdx.x >> 3) * 128;
    const int e0   = eg * EG;
    char* obuf = lds + 65536 + w * 8192;          // wave-private 8 KB
    char* blds = lds + 131072;                    // 8 experts x 512 B bias

    // X fragments, loaded once: rows n0 + wr*32 + m*16 + l15, k = kk*32+kg*8
    bf16x8 a[2][4];
    {
        const __bf16* Xp = Xb + (size_t)(n0 + wr*32 + l15) * DD + kg*8;
        #pragma unroll
        for (int m = 0; m < 2; ++m)
            #pragma unroll
            for (int kk = 0; kk < 4; ++kk)
                a[m][kk] = *(const bf16x8*)(Xp + m*16*DD + kk*32);
    }

    // prologue: stage bias for all EG experts -> LDS (4 KB, one f32x4/thread)
    if (t < 256) {
        f32x4 v = ((const f32x4*)(Bias + e0*DD))[t];
        *(f32x4*)(blds + t*16) = v;
    }

    // prologue: stage W[e0] -> buffer 0 (each wave stages 4 KB via 4 glls)
    {
        const char* src = (const char*)WTs + (size_t)e0 * 32768 + w*4096 + lane*16;
        char* dst = lds + w*4096;
        #pragma unroll
        for (int i = 0; i < 4; ++i) gll16(src + i*1024, dst + i*1024);
    }
    __syncthreads();

    int cur = 0;
    for (int ei = 0; ei < EG; ++ei) {
        const int e = e0 + ei;

        // prefetch next expert's W into the other buffer (stays in flight)
        if (ei + 1 < EG) {
            const char* src = (const char*)WTs + (size_t)(e+1) * 32768 + w*4096 + lane*16;
            char* dst = lds + (cur ^ 1) * 32768 + w*4096;
            #pragma unroll
            for (int i = 0; i < 4; ++i) gll16(src + i*1024, dst + i*1024);
        }

        // bias via LDS (lgkm only — no vmcnt wait in the loop)
        f32x4 acc[2][4];
        #pragma unroll
        for (int n = 0; n < 4; ++n) {
            f32x4 bv = *(const f32x4*)(blds + ei*512 + wc*256 + n*64 + kg*16);
            acc[0][n] = bv; acc[1][n] = bv;
        }

        // compute
        const char* buf = lds + cur * 32768;
        #pragma unroll
        for (int kk = 0; kk < 4; ++kk) {
            bf16x8 b[4];
            #pragma unroll
            for (int n = 0; n < 4; ++n) {
                int f = wc*64 + n*16 + l15;
                int off = f*256 + (kk*32 + kg*8)*2;
                off ^= (l15 & 7) << 4;
                b[n] = *(const bf16x8*)(buf + off);
            }
            #pragma unroll
            for (int m = 0; m < 2; ++m)
                #pragma unroll
                for (int n = 0; n < 4; ++n)
                    acc[m][n] = __builtin_amdgcn_mfma_f32_16x16x32_bf16(
                        b[n], a[m][kk], acc[m][n], 0, 0, 0);
        }

        // stage acc -> wave-private obuf: row = m*16+l15 (0..31), 256 B/row
        #pragma unroll
        for (int m = 0; m < 2; ++m) {
            #pragma unroll
            for (int n = 0; n < 4; ++n) {
                int row = m*16 + l15;
                int off = row*256 + n*64 + kg*16;
                off ^= (row & 7) << 4;
                *(f32x4*)(obuf + off) = acc[m][n];
            }
        }
        // no barrier: same wave reads its own slice (lgkm-ordered)

        // readback + stores: per inst 16 lanes x 16 B = 256 B contiguous per
        // row, 4 rows per inst.
        {
            const int row_off = lane >> 4;       // 0..3
            const int c16 = lane & 15;           // 16 lanes -> 256 B run
            #pragma unroll
            for (int rg = 0; rg < 8; ++rg) {     // 32 rows / 4 per inst
                int row = rg*4 + row_off;
                int off = row*256 + c16*16;
                off ^= (row & 7) << 4;
                f32x4 v = *(const f32x4*)(obuf + off);
                *(f32x4*)(O + (size_t)(n0 + wr*32 + row) * (EE*DD)
                            + e*DD + wc*64 + c16*4) = v;
            }
        }

        // counted barrier: vm queue here = [prev leftovers..., glls(4), stores(8)].
        // vmcnt(8) retires the glls (next W buffer ready) and anything older;
        // keeps the 8 newest (this expert's stores) in flight through the
        // next compute phase.
        if (ei + 1 < EG) {
            __builtin_amdgcn_sched_barrier(0);
            asm volatile("s_waitcnt vmcnt(8)" ::: "memory");
            __builtin_amdgcn_s_barrier();
            __builtin_amdgcn_sched_barrier(0);
        }
        cur ^= 1;
    }
}

// ---------- fallback (round-0 kernel, used if ws too small) ----------
__global__ __launch_bounds__(256, 2)
void experts_gemm_fb(const float* __restrict__ X,
                     const float* __restrict__ W,
                     const float* __restrict__ Bias,
                     float* __restrict__ O)
{
    constexpr int BM = 128;
    __shared__ __align__(16) char lds[BM*DD*2 + DD*DD*2];
    __bf16* As = (__bf16*)lds;
    __bf16* Bs = (__bf16*)(lds + BM*DD*2);

    const int t   = threadIdx.x;
    const int e   = blockIdx.x & (EE - 1);
    const int n0  = (blockIdx.x >> 6) * BM;

    {
        const float4* Xg = (const float4*)(X + (size_t)n0 * DD);
        #pragma unroll
        for (int i = 0; i < 16; ++i) {
            int ft = i * 256 + t;
            float4 v = Xg[ft];
            int n = ft >> 5, d0 = (ft & 31) << 2;
            bf16x4 p;
            p[0]=(__bf16)v.x; p[1]=(__bf16)v.y; p[2]=(__bf16)v.z; p[3]=(__bf16)v.w;
            int off = n * 256 + d0 * 2;
            off ^= (n & 7) << 4;
            *(bf16x4*)((char*)As + off) = p;
        }
    }
    {
        const float4* Wg = (const float4*)(W + (size_t)e * DD * DD);
        #pragma unroll
        for (int i = 0; i < 4; ++i) {
            int bb = i * 256 + t;
            int db = bb >> 5, fb = bb & 31;
            float4 r0 = Wg[(db*4+0)*32 + fb];
            float4 r1 = Wg[(db*4+1)*32 + fb];
            float4 r2 = Wg[(db*4+2)*32 + fb];
            float4 r3 = Wg[(db*4+3)*32 + fb];
            const float* q0=(const float*)&r0; const float* q1=(const float*)&r1;
            const float* q2=(const float*)&r2; const float* q3=(const float*)&r3;
            #pragma unroll
            for (int j = 0; j < 4; ++j) {
                bf16x4 p;
                p[0]=(__bf16)q0[j]; p[1]=(__bf16)q1[j];
                p[2]=(__bf16)q2[j]; p[3]=(__bf16)q3[j];
                int f = fb * 4 + j;
                int off = f * 256 + db * 8;
                off ^= (f & 7) << 4;
                *(bf16x4*)((char*)Bs + off) = p;
            }
        }
    }
    __syncthreads();

    const int lane = t & 63, w = t >> 6;
    const int wr = w >> 1, wc = w & 1;
    const int l15 = lane & 15, kg = lane >> 4;

    f32x4 acc[4][4];
    #pragma unroll
    for (int m = 0; m < 4; ++m)
        #pragma unroll
        for (int n = 0; n < 4; ++n) {
            acc[m][n][0]=0.f; acc[m][n][1]=0.f; acc[m][n][2]=0.f; acc[m][n][3]=0.f;
        }

    float bias[4];
    #pragma unroll
    for (int n = 0; n < 4; ++n) bias[n] = Bias[e*DD + wc*64 + n*16 + l15];

    #pragma unroll
    for (int kk = 0; kk < 4; ++kk) {
        int koff = kk * 32 + kg * 8;
        bf16x8 av[4], bvv[4];
        #pragma unroll
        for (int m = 0; m < 4; ++m) {
            int row = wr*64 + m*16 + l15;
            int off = row * 256 + koff * 2;
            off ^= (row & 7) << 4;
            av[m] = *(const bf16x8*)((const char*)As + off);
        }
        #pragma unroll
        for (int n = 0; n < 4; ++n) {
            int col = wc*64 + n*16 + l15;
            int off = col * 256 + koff * 2;
            off ^= (col & 7) << 4;
            bvv[n] = *(const bf16x8*)((const char*)Bs + off);
        }
        #pragma unroll
        for (int m = 0; m < 4; ++m)
            #pragma unroll
            for (int n = 0; n < 4; ++n)
                acc[m][n] = __builtin_amdgcn_mfma_f32_16x16x32_bf16(
                    av[m], bvv[n], acc[m][n], 0, 0, 0);
    }

    float* Op = O + (size_t)n0 * (EE*DD) + (size_t)e * DD;
    #pragma unroll
    for (int m = 0; m < 4; ++m)
        #pragma unroll
        for (int n = 0; n < 4; ++n) {
            int cg = wc*64 + n*16 + l15;
            #pragma unroll
            for (int r = 0; r < 4; ++r) {
                int rg = wr*64 + m*16 + kg*4 + r;
                Op[(size_t)rg * (EE*DD) + cg] = acc[m][n][r] + bias[n];
            }
        }
}

extern "C" void kernel_launch(void* const* d_in, const int* in_sizes, int n_in,
                              void* d_out, int out_size, void* d_ws, size_t ws_size,
                              hipStream_t stream) {
    const float* X = (const float*)d_in[0];
    const float* W = (const float*)d_in[1];
    const float* B = (const float*)d_in[2];
    float* O = (float*)d_out;

    const size_t xb_bytes = (size_t)NN * DD * sizeof(__bf16);      // 4 MiB
    const size_t wt_bytes = (size_t)EE * DD * DD * sizeof(__bf16); // 2 MiB

    if (ws_size >= xb_bytes + wt_bytes) {
        __bf16* Xb  = (__bf16*)d_ws;
        __bf16* WTs = (__bf16*)((char*)d_ws + xb_bytes);
        cvt_x<<<NN * DD / 8 / 256, 256, 0, stream>>>(X, Xb);
        cvt_wt<<<EE, 256, 0, stream>>>(W, WTs);
        experts_gemm_ls<<<(NN / 128) * (EE / EG), 512, 0, stream>>>(Xb, WTs, B, O);
    } else {
        experts_gemm_fb<<<(NN / 128) * EE, 256, 0, stream>>>(X, W, B, O);
    }
}